// Round 5
// baseline (810.364 us; speedup 1.0000x reference)
//
#include <hip/hip_runtime.h>
#include <cstdint>

#define N_NODES 50000
#define N_EDGES 800000
#define IN_FEATS 128
#define HID 64
#define HEADS 3
#define NUM_CLASSES 8
#define ATTN_SLOPE 0.2f
#define ACT_SLOPE 0.01f

__device__ __forceinline__ float lrelu(float x, float s) { return x > 0.f ? x : s * x; }

// ---------- CSR build (once per call; edges are layer-invariant) ----------
__global__ void k_deg(const int* __restrict__ dst, int* __restrict__ deg, int E) {
    int i = blockIdx.x * blockDim.x + threadIdx.x;
    if (i < E) atomicAdd(&deg[dst[i]], 1);
}

// hierarchical scan: scan1 (25 blocks x 2048 elems) -> scan2 (1 wave) -> scan3
__global__ __launch_bounds__(256) void k_scan1(const int* __restrict__ deg, int* __restrict__ off,
                                               int* __restrict__ bsum, int n) {
    __shared__ int wtot[4];
    int tid = threadIdx.x;
    int lane = tid & 63, wid = tid >> 6;
    int base = blockIdx.x * 2048 + tid * 8;
    int v[8];
    if (base + 8 <= n) {
        int4 a = *(const int4*)&deg[base];
        int4 b = *(const int4*)&deg[base + 4];
        v[0] = a.x; v[1] = a.y; v[2] = a.z; v[3] = a.w;
        v[4] = b.x; v[5] = b.y; v[6] = b.z; v[7] = b.w;
    } else {
#pragma unroll
        for (int j = 0; j < 8; ++j) v[j] = (base + j < n) ? deg[base + j] : 0;
    }
    int s[8];
    s[0] = v[0];
#pragma unroll
    for (int j = 1; j < 8; ++j) s[j] = s[j - 1] + v[j];
    int t = s[7];
    int incl = t;
    for (int o = 1; o < 64; o <<= 1) {
        int u = __shfl_up(incl, o);
        if (lane >= o) incl += u;
    }
    int excl = incl - t;
    if (lane == 63) wtot[wid] = incl;
    __syncthreads();
    int wprefix = 0;
    for (int w = 0; w < wid; ++w) wprefix += wtot[w];
    int base_off = wprefix + excl;
#pragma unroll
    for (int j = 0; j < 8; ++j)
        if (base + j < n) off[base + j] = base_off + s[j] - v[j];
    if (tid == 0) bsum[blockIdx.x] = wtot[0] + wtot[1] + wtot[2] + wtot[3];
}

__global__ __launch_bounds__(64) void k_scan2(int* __restrict__ bsum, int nb) {
    int tid = threadIdx.x;
    int v = (tid < nb) ? bsum[tid] : 0;
    int incl = v;
    for (int o = 1; o < 64; o <<= 1) {
        int u = __shfl_up(incl, o);
        if (tid >= o) incl += u;
    }
    if (tid < nb) bsum[tid] = incl - v;   // exclusive
}

__global__ __launch_bounds__(256) void k_scan3(int* __restrict__ off, const int* __restrict__ bsum,
                                               int n, int E) {
    int i = blockIdx.x * blockDim.x + threadIdx.x;
    if (i < n) off[i] += bsum[i >> 11];
    if (i == 0) off[n] = E;
}

__global__ void k_fill(const int* __restrict__ src, const int* __restrict__ dst,
                       const int* __restrict__ off, int* __restrict__ cur,
                       int* __restrict__ ssrc, int E) {
    int i = blockIdx.x * blockDim.x + threadIdx.x;
    if (i < E) {
        int d = dst[i];
        int p = atomicAdd(&cur[d], 1);
        ssrc[off[d] + p] = src[i];
    }
}

// ---------- feat = h @ W, register-microtiled, fused el/er ----------
__global__ __launch_bounds__(256) void k_gemm(const float* __restrict__ h, const float* __restrict__ W,
                                              const float* __restrict__ al, const float* __restrict__ ar,
                                              float* __restrict__ feat,
                                              float* __restrict__ el, float* __restrict__ er,
                                              int N, int din) {
    __shared__ float Hl[128][68];
    __shared__ float Wl[64][64];
    int tid = threadIdx.x;
    int cg = tid & 15;
    int rg = tid >> 4;
    int row0 = blockIdx.x * 128;
    int head = blockIdx.y;
    int c0 = head * 64;

    float acc[8][4];
#pragma unroll
    for (int i = 0; i < 8; ++i)
#pragma unroll
        for (int c = 0; c < 4; ++c) acc[i][c] = 0.f;

    for (int k0 = 0; k0 < din; k0 += 64) {
        for (int j = tid; j < 1024; j += 256) {
            int k = j >> 4, c4 = (j & 15) << 2;
            *(float4*)&Wl[k][c4] = *(const float4*)&W[(size_t)(k0 + k) * 192 + c0 + c4];
        }
        for (int j = tid; j < 2048; j += 256) {
            int r = j >> 4, kk = (j & 15) << 2;
            int row = row0 + r;
            float4 v = make_float4(0.f, 0.f, 0.f, 0.f);
            if (row < N) v = *(const float4*)&h[(size_t)row * din + k0 + kk];
            *(float4*)&Hl[r][kk] = v;
        }
        __syncthreads();

        for (int k = 0; k < 64; k += 4) {
            float4 w0 = *(const float4*)&Wl[k + 0][cg << 2];
            float4 w1 = *(const float4*)&Wl[k + 1][cg << 2];
            float4 w2 = *(const float4*)&Wl[k + 2][cg << 2];
            float4 w3 = *(const float4*)&Wl[k + 3][cg << 2];
#pragma unroll
            for (int i = 0; i < 8; ++i) {
                float4 hv = *(const float4*)&Hl[rg + 16 * i][k];
                acc[i][0] += hv.x * w0.x + hv.y * w1.x + hv.z * w2.x + hv.w * w3.x;
                acc[i][1] += hv.x * w0.y + hv.y * w1.y + hv.z * w2.y + hv.w * w3.y;
                acc[i][2] += hv.x * w0.z + hv.y * w1.z + hv.z * w2.z + hv.w * w3.z;
                acc[i][3] += hv.x * w0.w + hv.y * w1.w + hv.z * w2.w + hv.w * w3.w;
            }
        }
        __syncthreads();
    }

    float alv0 = al[c0 + (cg << 2) + 0], alv1 = al[c0 + (cg << 2) + 1];
    float alv2 = al[c0 + (cg << 2) + 2], alv3 = al[c0 + (cg << 2) + 3];
    float arv0 = ar[c0 + (cg << 2) + 0], arv1 = ar[c0 + (cg << 2) + 1];
    float arv2 = ar[c0 + (cg << 2) + 2], arv3 = ar[c0 + (cg << 2) + 3];
#pragma unroll
    for (int i = 0; i < 8; ++i) {
        int row = row0 + rg + 16 * i;
        bool ok = (row < N);
        float4 a4 = make_float4(acc[i][0], acc[i][1], acc[i][2], acc[i][3]);
        if (ok) *(float4*)&feat[(size_t)row * 192 + c0 + (cg << 2)] = a4;
        float pl = a4.x * alv0 + a4.y * alv1 + a4.z * alv2 + a4.w * alv3;
        float pr = a4.x * arv0 + a4.y * arv1 + a4.z * arv2 + a4.w * arv3;
        for (int o = 1; o < 16; o <<= 1) {
            pl += __shfl_xor(pl, o);
            pr += __shfl_xor(pr, o);
        }
        if (ok && cg == 0) {
            el[row * HEADS + head] = pl;
            er[row * HEADS + head] = pr;
        }
    }
}

// ---------- edge softmax + aggregate + bias + leakyrelu + head-mean ----------
// One wave per dst node, lanes = 64 feats, all 3 heads in one edge pass.
// ebuf entries beyond cnt are zero-weight (s=0,x=0) so the gather loop runs
// over a padded multiple of 4 with NO tail; 2-stage software pipeline keeps
// ~24 independent gathers in flight per wave.
__global__ __launch_bounds__(256) void k_agg(const int* __restrict__ off, const int* __restrict__ ssrc,
                                             const float* __restrict__ el, const float* __restrict__ er,
                                             const float* __restrict__ feat, const float* __restrict__ b,
                                             float* __restrict__ hout, int N) {
    __shared__ float4 ebuf[4][64];
    int wib = threadIdx.x >> 6;
    int wid = (blockIdx.x * blockDim.x + threadIdx.x) >> 6;
    int lane = threadIdx.x & 63;
    if (wid >= N) return;
    int start = off[wid], end = off[wid + 1];
    int cnt = end - start;
    float er0 = er[wid * HEADS + 0];
    float er1 = er[wid * HEADS + 1];
    float er2 = er[wid * HEADS + 2];
    float acc0 = 0.f, acc1 = 0.f, acc2 = 0.f;
    float den0 = 0.f, den1 = 0.f, den2 = 0.f;

#define GATHER_PIPELINE(PAD)                                                        \
    {                                                                               \
        int padded = (PAD);                                                         \
        if (padded > 0) {                                                           \
            float4 v0 = ebuf[wib][0], v1 = ebuf[wib][1];                            \
            float4 v2 = ebuf[wib][2], v3 = ebuf[wib][3];                            \
            const float* f0 = feat + (size_t)__float_as_int(v0.x) * 192 + lane;     \
            const float* f1 = feat + (size_t)__float_as_int(v1.x) * 192 + lane;     \
            const float* f2 = feat + (size_t)__float_as_int(v2.x) * 192 + lane;     \
            const float* f3 = feat + (size_t)__float_as_int(v3.x) * 192 + lane;     \
            float p00 = f0[0], p01 = f0[64], p02 = f0[128];                         \
            float p10 = f1[0], p11 = f1[64], p12 = f1[128];                         \
            float p20 = f2[0], p21 = f2[64], p22 = f2[128];                         \
            float p30 = f3[0], p31 = f3[64], p32 = f3[128];                         \
            for (int t = 4; t < padded; t += 4) {                                   \
                float4 u0 = ebuf[wib][t + 0], u1 = ebuf[wib][t + 1];                \
                float4 u2 = ebuf[wib][t + 2], u3 = ebuf[wib][t + 3];                \
                const float* g0 = feat + (size_t)__float_as_int(u0.x) * 192 + lane; \
                const float* g1 = feat + (size_t)__float_as_int(u1.x) * 192 + lane; \
                const float* g2 = feat + (size_t)__float_as_int(u2.x) * 192 + lane; \
                const float* g3 = feat + (size_t)__float_as_int(u3.x) * 192 + lane; \
                float q00 = g0[0], q01 = g0[64], q02 = g0[128];                     \
                float q10 = g1[0], q11 = g1[64], q12 = g1[128];                     \
                float q20 = g2[0], q21 = g2[64], q22 = g2[128];                     \
                float q30 = g3[0], q31 = g3[64], q32 = g3[128];                     \
                acc0 += v0.y * p00; acc1 += v0.z * p01; acc2 += v0.w * p02;         \
                acc0 += v1.y * p10; acc1 += v1.z * p11; acc2 += v1.w * p12;         \
                acc0 += v2.y * p20; acc1 += v2.z * p21; acc2 += v2.w * p22;         \
                acc0 += v3.y * p30; acc1 += v3.z * p31; acc2 += v3.w * p32;         \
                v0 = u0; v1 = u1; v2 = u2; v3 = u3;                                 \
                p00 = q00; p01 = q01; p02 = q02;                                    \
                p10 = q10; p11 = q11; p12 = q12;                                    \
                p20 = q20; p21 = q21; p22 = q22;                                    \
                p30 = q30; p31 = q31; p32 = q32;                                    \
            }                                                                       \
            acc0 += v0.y * p00; acc1 += v0.z * p01; acc2 += v0.w * p02;             \
            acc0 += v1.y * p10; acc1 += v1.z * p11; acc2 += v1.w * p12;             \
            acc0 += v2.y * p20; acc1 += v2.z * p21; acc2 += v2.w * p22;             \
            acc0 += v3.y * p30; acc1 += v3.z * p31; acc2 += v3.w * p32;             \
        }                                                                           \
    }

    if (cnt <= 64) {
        int s0 = 0;
        float ea = -3.4e38f, eb = -3.4e38f, ec = -3.4e38f;
        if (lane < cnt) {
            s0 = ssrc[start + lane];
            ea = lrelu(el[s0 * HEADS + 0] + er0, ATTN_SLOPE);
            eb = lrelu(el[s0 * HEADS + 1] + er1, ATTN_SLOPE);
            ec = lrelu(el[s0 * HEADS + 2] + er2, ATTN_SLOPE);
        }
        float ma = ea, mb = eb, mc = ec;
        for (int o = 32; o > 0; o >>= 1) {
            ma = fmaxf(ma, __shfl_xor(ma, o));
            mb = fmaxf(mb, __shfl_xor(mb, o));
            mc = fmaxf(mc, __shfl_xor(mc, o));
        }
        float xa = (lane < cnt) ? __expf(ea - ma) : 0.f;
        float xb = (lane < cnt) ? __expf(eb - mb) : 0.f;
        float xc = (lane < cnt) ? __expf(ec - mc) : 0.f;
        float da = xa, db = xb, dc = xc;
        for (int o = 32; o > 0; o >>= 1) {
            da += __shfl_xor(da, o);
            db += __shfl_xor(db, o);
            dc += __shfl_xor(dc, o);
        }
        den0 = da; den1 = db; den2 = dc;
        ebuf[wib][lane] = make_float4(__int_as_float(s0), xa, xb, xc);
        GATHER_PIPELINE((cnt + 3) & ~3)
    } else {
        float ma = -3.4e38f, mb = -3.4e38f, mc = -3.4e38f;
        for (int j = start + lane; j < end; j += 64) {
            int s = ssrc[j];
            ma = fmaxf(ma, lrelu(el[s * HEADS + 0] + er0, ATTN_SLOPE));
            mb = fmaxf(mb, lrelu(el[s * HEADS + 1] + er1, ATTN_SLOPE));
            mc = fmaxf(mc, lrelu(el[s * HEADS + 2] + er2, ATTN_SLOPE));
        }
        for (int o = 32; o > 0; o >>= 1) {
            ma = fmaxf(ma, __shfl_xor(ma, o));
            mb = fmaxf(mb, __shfl_xor(mb, o));
            mc = fmaxf(mc, __shfl_xor(mc, o));
        }
        float da = 0.f, db = 0.f, dc = 0.f;
        for (int j0 = start; j0 < end; j0 += 64) {
            int jj = j0 + lane;
            int s0 = 0;
            float xa = 0.f, xb = 0.f, xc = 0.f;
            if (jj < end) {
                s0 = ssrc[jj];
                xa = __expf(lrelu(el[s0 * HEADS + 0] + er0, ATTN_SLOPE) - ma);
                xb = __expf(lrelu(el[s0 * HEADS + 1] + er1, ATTN_SLOPE) - mb);
                xc = __expf(lrelu(el[s0 * HEADS + 2] + er2, ATTN_SLOPE) - mc);
            }
            da += xa; db += xb; dc += xc;
            ebuf[wib][lane] = make_float4(__int_as_float(s0), xa, xb, xc);
            int c = min(64, end - j0);
            GATHER_PIPELINE((c + 3) & ~3)
        }
        for (int o = 32; o > 0; o >>= 1) {
            da += __shfl_xor(da, o);
            db += __shfl_xor(db, o);
            dc += __shfl_xor(dc, o);
        }
        den0 = da; den1 = db; den2 = dc;
    }
#undef GATHER_PIPELINE

    float v0 = (cnt > 0) ? acc0 / den0 : 0.f;
    float v1 = (cnt > 0) ? acc1 / den1 : 0.f;
    float v2 = (cnt > 0) ? acc2 / den2 : 0.f;
    float hsum = lrelu(v0 + b[lane], ACT_SLOPE)
               + lrelu(v1 + b[64 + lane], ACT_SLOPE)
               + lrelu(v2 + b[128 + lane], ACT_SLOPE);
    hout[wid * 64 + lane] = hsum * (1.f / 3.f);
}

// ---------- logits = h @ Wo + bo ----------
__global__ __launch_bounds__(256) void k_out(const float* __restrict__ h, const float* __restrict__ Wo,
                                             const float* __restrict__ bo, float* __restrict__ out, int N) {
    __shared__ float Hl[32][65];
    __shared__ float Wl[64 * 8];
    int tid = threadIdx.x;
    int n0 = blockIdx.x * 32;
    for (int i = tid; i < 32 * 64; i += 256) {
        int r = i >> 6, k = i & 63;
        Hl[r][k] = (n0 + r < N) ? h[(n0 + r) * 64 + k] : 0.f;
    }
    for (int i = tid; i < 512; i += 256) Wl[i] = Wo[i];
    __syncthreads();
    int r = tid >> 3, c = tid & 7;
    float acc = 0.f;
    for (int k = 0; k < 64; ++k) acc += Hl[r][k] * Wl[k * 8 + c];
    int row = n0 + r;
    if (row < N) out[row * 8 + c] = acc + bo[c];
}

extern "C" void kernel_launch(void* const* d_in, const int* in_sizes, int n_in,
                              void* d_out, int out_size, void* d_ws, size_t ws_size,
                              hipStream_t stream) {
    const float* x  = (const float*)d_in[0];
    const int* src  = (const int*)d_in[1];
    const int* dst  = (const int*)d_in[2];
    const float *W[5], *b[5], *al[5], *ar[5];
    for (int l = 0; l < 5; ++l) {
        W[l]  = (const float*)d_in[3 + l * 4];
        b[l]  = (const float*)d_in[4 + l * 4];
        al[l] = (const float*)d_in[5 + l * 4];
        ar[l] = (const float*)d_in[6 + l * 4];
    }
    const float* Wo = (const float*)d_in[23];
    const float* bo = (const float*)d_in[24];
    float* out = (float*)d_out;

    char* ws = (char*)d_ws;
    auto alloc = [&](size_t bytes) {
        char* p = ws;
        ws += (bytes + 255) & ~size_t(255);
        return p;
    };
    float* feat = (float*)alloc(sizeof(float) * (size_t)N_NODES * 192);
    float* el   = (float*)alloc(sizeof(float) * (size_t)N_NODES * HEADS);
    float* er   = (float*)alloc(sizeof(float) * (size_t)N_NODES * HEADS);
    float* h0   = (float*)alloc(sizeof(float) * (size_t)N_NODES * 64);
    float* h1   = (float*)alloc(sizeof(float) * (size_t)N_NODES * 64);
    int* deg    = (int*)alloc(sizeof(int) * N_NODES);
    int* off    = (int*)alloc(sizeof(int) * (N_NODES + 1));
    int* cur    = (int*)alloc(sizeof(int) * N_NODES);
    int* ssrc   = (int*)alloc(sizeof(int) * N_EDGES);
    int* bsum   = (int*)alloc(sizeof(int) * 64);

    const int NB = (N_NODES + 2047) / 2048;   // 25 (<=64 required by k_scan2)
    hipMemsetAsync(deg, 0, sizeof(int) * N_NODES, stream);
    hipMemsetAsync(cur, 0, sizeof(int) * N_NODES, stream);
    k_deg<<<(N_EDGES + 255) / 256, 256, 0, stream>>>(dst, deg, N_EDGES);
    k_scan1<<<NB, 256, 0, stream>>>(deg, off, bsum, N_NODES);
    k_scan2<<<1, 64, 0, stream>>>(bsum, NB);
    k_scan3<<<(N_NODES + 255) / 256, 256, 0, stream>>>(off, bsum, N_NODES, N_EDGES);
    k_fill<<<(N_EDGES + 255) / 256, 256, 0, stream>>>(src, dst, off, cur, ssrc, N_EDGES);

    const float* hin = x;
    float* hbuf[2] = {h0, h1};
    int din = IN_FEATS;
    for (int l = 0; l < 5; ++l) {
        dim3 ggrid((N_NODES + 127) / 128, HEADS);
        k_gemm<<<ggrid, 256, 0, stream>>>(hin, W[l], al[l], ar[l], feat, el, er, N_NODES, din);
        float* hn = hbuf[l & 1];
        k_agg<<<(N_NODES * 64 + 255) / 256, 256, 0, stream>>>(off, ssrc, el, er, feat, b[l], hn, N_NODES);
        hin = hn;
        din = HID;
    }
    k_out<<<(N_NODES + 31) / 32, 256, 0, stream>>>(hin, Wo, bo, out, N_NODES);
}